// Round 20
// baseline (169.135 us; speedup 1.0000x reference)
//
#include <hip/hip_runtime.h>
#include <stdint.h>

typedef unsigned short u16;
typedef __attribute__((ext_vector_type(8))) short bf16x8;
typedef __attribute__((ext_vector_type(4))) float f32x4;

#define NN 2048
#define NEDGE 32768
#define NBLK 2048      // mlp1 split-K blocks
#define KC 128         // j-chunk per mlp1 block (NBLK*KC == 262144)
#define NRG 32         // reduce ranges (NBLK/64)
#define PW 112         // padded N for mlp1 (7 tiles of 16; 100 real)

__device__ __forceinline__ float bf2f(uint32_t u) {
  union { uint32_t i; float f; } c; c.i = u << 16; return c.f;
}
__device__ __forceinline__ uint32_t f2bf(float f) {
  union { float f; uint32_t i; } c; c.f = f;
  uint32_t x = c.i;
  return (x + 0x7fffu + ((x >> 16) & 1u)) >> 16;
}

// ---------- prep: conv_w cvt (0..47), gW1/gW2 transpose (48..111), csr-init (112..119) ----------
__global__ void k_prep(const float4* __restrict__ cw, uint2* __restrict__ wtb,
                       const float* __restrict__ g1, const float* __restrict__ g2,
                       u16* __restrict__ o1, u16* __restrict__ o2,
                       int* __restrict__ cnt, int* __restrict__ cursor) {
  int blk = blockIdx.x;
  if (blk < 48) {
    int i = blk * 256 + threadIdx.x;         // 12288 exact (49152/4)
    float4 v = cw[i];
    uint2 o;
    o.x = f2bf(v.x) | (f2bf(v.y) << 16);
    o.y = f2bf(v.z) | (f2bf(v.w) << 16);
    wtb[i] = o;
  } else if (blk < 112) {
    int i = (blk - 48) * 256 + threadIdx.x;  // 16384 exact
    int r = i >> 7, c = i & 127;
    o1[i] = (u16)f2bf(g1[c * 128 + r]);
    o2[i] = (u16)f2bf(g2[c * 128 + r]);
  } else {
    int i = (blk - 112) * 256 + threadIdx.x; // 2048 exact
    cnt[i] = 1; cursor[i] = 0;               // self-loop baseline
  }
}

// ---------- CSR build (parallel chain) ----------
__global__ void k_count(const int* __restrict__ edge, int* __restrict__ cnt) {
  int i = blockIdx.x * 256 + threadIdx.x;
  if (i < NEDGE) atomicAdd(&cnt[edge[NEDGE + i]], 1);
}

__global__ __launch_bounds__(1024) void k_scan(const int* __restrict__ cnt, int* __restrict__ rowp) {
  __shared__ int s[1024];
  int t = threadIdx.x;
  int c0 = cnt[2 * t], c1 = cnt[2 * t + 1];
  s[t] = c0 + c1;
  __syncthreads();
  for (int off = 1; off < 1024; off <<= 1) {
    int v = (t >= off) ? s[t - off] : 0;
    __syncthreads();
    s[t] += v;
    __syncthreads();
  }
  int excl = s[t] - c0 - c1;
  rowp[2 * t] = excl;
  rowp[2 * t + 1] = excl + c0;
  if (t == 1023) rowp[2048] = s[t];
}

__global__ void k_fill(const int* __restrict__ edge, const int* __restrict__ cnt,
                       const int* __restrict__ rowp, int* __restrict__ cursor,
                       int* __restrict__ colx, float* __restrict__ wgt) {
  int i = blockIdx.x * 256 + threadIdx.x;
  if (i >= NEDGE + NN) return;
  int s, d;
  if (i < NEDGE) { s = edge[i]; d = edge[NEDGE + i]; }
  else { s = i - NEDGE; d = s; }
  float wv = rsqrtf((float)cnt[s] * (float)cnt[d]);
  int pos = atomicAdd(&cursor[d], 1);
  int idx = rowp[d] + pos;
  colx[idx] = s;
  wgt[idx] = wv;
}

// ---------- conv GEMM, 64-row tiles (1024 blocks, 16 waves/CU):
// A = fp32 x inline-cvt (reg-staged, swizzled), B = bf16 global_load_lds ----------
__global__ __launch_bounds__(256) void k_gemmf(
    const float* __restrict__ A, const u16* __restrict__ Bt,
    const float* __restrict__ bias, u16* __restrict__ C,
    int K, int bExtra)
{
  __shared__ u16 lA[64 * 64];     // 8 KB
  __shared__ u16 lB[128 * 64];    // 16 KB
  const int t = threadIdx.x;
  const int Mbase = blockIdx.x * 64;
  const size_t aBase = (size_t)Mbase * 128 + (size_t)(Mbase >> 11) * bExtra;
  const int w = t >> 6, l = t & 63;
  const int wrN = w * 32;
  const int lm = l & 15, lkh = l >> 4;
  const int rph0 = t >> 3, pc = t & 7;       // B staging
  const int row4 = t >> 2, qf = t & 3;       // A staging: row, quarter (16 fp32)
  f32x4 acc[4][2];
#pragma unroll
  for (int i = 0; i < 4; ++i)
#pragma unroll
    for (int j = 0; j < 2; ++j)
      acc[i][j] = (f32x4){0.f, 0.f, 0.f, 0.f};

  for (int kc = 0; kc < K; kc += 64) {
    __syncthreads();
#pragma unroll
    for (int it = 0; it < 4; ++it) {
      int r = it * 32 + rph0;
      int lc = pc ^ (r & 7);
      char* dstB = (char*)lB + it * 4096 + w * 1024;
      __builtin_amdgcn_global_load_lds(
          (const void*)(Bt + (size_t)r * K + kc + lc * 8), dstB, 16, 0, 0);
    }
    {
      const float4* src = (const float4*)(A + aBase + (size_t)row4 * 128 + kc + qf * 16);
      float4 f[4];
#pragma unroll
      for (int c = 0; c < 4; ++c) f[c] = src[c];
      uint4 pk0, pk1;
      pk0.x = f2bf(f[0].x) | (f2bf(f[0].y) << 16);
      pk0.y = f2bf(f[0].z) | (f2bf(f[0].w) << 16);
      pk0.z = f2bf(f[1].x) | (f2bf(f[1].y) << 16);
      pk0.w = f2bf(f[1].z) | (f2bf(f[1].w) << 16);
      pk1.x = f2bf(f[2].x) | (f2bf(f[2].y) << 16);
      pk1.y = f2bf(f[2].z) | (f2bf(f[2].w) << 16);
      pk1.z = f2bf(f[3].x) | (f2bf(f[3].y) << 16);
      pk1.w = f2bf(f[3].z) | (f2bf(f[3].w) << 16);
      int ch0 = qf * 2, ch1 = qf * 2 + 1;
      *(uint4*)((char*)lA + row4 * 128 + ((ch0 ^ (row4 & 7)) << 4)) = pk0;
      *(uint4*)((char*)lA + row4 * 128 + ((ch1 ^ (row4 & 7)) << 4)) = pk1;
    }
    __syncthreads();
#pragma unroll
    for (int kk = 0; kk < 2; ++kk) {
      int lc = kk * 4 + lkh;
      bf16x8 af[4], bfr[2];
#pragma unroll
      for (int i = 0; i < 4; ++i) {
        int R = i * 16 + lm;
        af[i] = *(const bf16x8*)((const char*)lA + R * 128 + ((lc ^ (R & 7)) << 4));
      }
#pragma unroll
      for (int j = 0; j < 2; ++j) {
        int R = wrN + j * 16 + lm;
        bfr[j] = *(const bf16x8*)((const char*)lB + R * 128 + ((lc ^ (R & 7)) << 4));
      }
#pragma unroll
      for (int i = 0; i < 4; ++i)
#pragma unroll
        for (int j = 0; j < 2; ++j)
          acc[i][j] = __builtin_amdgcn_mfma_f32_16x16x32_bf16(af[i], bfr[j], acc[i][j], 0, 0, 0);
    }
  }
  const int rq = (l >> 4) * 4;
#pragma unroll
  for (int i = 0; i < 4; ++i) {
#pragma unroll
    for (int j = 0; j < 2; ++j) {
      int col = wrN + j * 16 + lm;
      float bv = bias[col];
#pragma unroll
      for (int q = 0; q < 4; ++q) {
        int row = Mbase + i * 16 + rq + q;
        float v = acc[i][j][q] + bv;
        v = fmaxf(v, 0.f);
        C[(size_t)row * 128 + col] = (u16)f2bf(v);
      }
    }
  }
}

// ---------- GCN GEMM, 64-row tiles (bf16 A, both via global_load_lds) ----------
__global__ __launch_bounds__(256) void k_gemm(
    const u16* __restrict__ A, const u16* __restrict__ Bt,
    const float* __restrict__ bias, u16* __restrict__ C,
    int K)
{
  __shared__ u16 lA[64 * 64];     // 8 KB
  __shared__ u16 lB[128 * 64];    // 16 KB
  const int t = threadIdx.x;
  const int Mbase = blockIdx.x * 64;
  const size_t aBase = (size_t)Mbase * 128;
  const int w = t >> 6, l = t & 63;
  const int wrN = w * 32;
  const int lm = l & 15, lkh = l >> 4;
  const int rph0 = t >> 3, pc = t & 7;
  f32x4 acc[4][2];
#pragma unroll
  for (int i = 0; i < 4; ++i)
#pragma unroll
    for (int j = 0; j < 2; ++j)
      acc[i][j] = (f32x4){0.f, 0.f, 0.f, 0.f};

  for (int kc = 0; kc < K; kc += 64) {
    __syncthreads();
#pragma unroll
    for (int it = 0; it < 2; ++it) {
      int r = it * 32 + rph0;
      int lc = pc ^ (r & 7);
      char* dstA = (char*)lA + it * 4096 + w * 1024;
      __builtin_amdgcn_global_load_lds(
          (const void*)(A + aBase + (size_t)r * 128 + kc + lc * 8), dstA, 16, 0, 0);
    }
#pragma unroll
    for (int it = 0; it < 4; ++it) {
      int r = it * 32 + rph0;
      int lc = pc ^ (r & 7);
      char* dstB = (char*)lB + it * 4096 + w * 1024;
      __builtin_amdgcn_global_load_lds(
          (const void*)(Bt + (size_t)r * K + kc + lc * 8), dstB, 16, 0, 0);
    }
    __syncthreads();
#pragma unroll
    for (int kk = 0; kk < 2; ++kk) {
      int lc = kk * 4 + lkh;
      bf16x8 af[4], bfr[2];
#pragma unroll
      for (int i = 0; i < 4; ++i) {
        int R = i * 16 + lm;
        af[i] = *(const bf16x8*)((const char*)lA + R * 128 + ((lc ^ (R & 7)) << 4));
      }
#pragma unroll
      for (int j = 0; j < 2; ++j) {
        int R = wrN + j * 16 + lm;
        bfr[j] = *(const bf16x8*)((const char*)lB + R * 128 + ((lc ^ (R & 7)) << 4));
      }
#pragma unroll
      for (int i = 0; i < 4; ++i)
#pragma unroll
        for (int j = 0; j < 2; ++j)
          acc[i][j] = __builtin_amdgcn_mfma_f32_16x16x32_bf16(af[i], bfr[j], acc[i][j], 0, 0, 0);
    }
  }
  const int rq = (l >> 4) * 4;
#pragma unroll
  for (int i = 0; i < 4; ++i) {
#pragma unroll
    for (int j = 0; j < 2; ++j) {
      int col = wrN + j * 16 + lm;
      float bv = bias[col];
#pragma unroll
      for (int q = 0; q < 4; ++q) {
        int row = Mbase + i * 16 + rq + q;
        float v = acc[i][j][q] + bv;
        v = fmaxf(v, 0.f);
        C[(size_t)row * 128 + col] = (u16)f2bf(v);
      }
    }
  }
}

// ---------- sparse gather: one wave per (b,v), 8-edge ILP, XCD swizzle ----------
__global__ __launch_bounds__(256) void k_gather(
    const u16* __restrict__ h, const int* __restrict__ rowp,
    const int* __restrict__ colx, const float* __restrict__ wgt,
    u16* __restrict__ out)
{
  int w = threadIdx.x >> 6, l = threadIdx.x & 63;
  int bid = blockIdx.x;
  int sb = (bid & 7) * 2048 + (bid >> 3);   // bijective XCD swizzle (16384 blocks)
  int p = sb * 4 + w;                       // 0..65535
  int b = p >> 11, v = p & 2047;
  int e0 = rowp[v], e1 = rowp[v + 1];
  const u16* hb = h + (size_t)b * (2048 * 128);
  float a0 = 0.f, a1 = 0.f;
  int e = e0;
  for (; e + 8 <= e1; e += 8) {
    int u0 = colx[e], u1 = colx[e + 1], u2 = colx[e + 2], u3 = colx[e + 3];
    int u4 = colx[e + 4], u5 = colx[e + 5], u6 = colx[e + 6], u7 = colx[e + 7];
    float w0 = wgt[e], w1 = wgt[e + 1], w2 = wgt[e + 2], w3 = wgt[e + 3];
    float w4 = wgt[e + 4], w5 = wgt[e + 5], w6 = wgt[e + 6], w7 = wgt[e + 7];
    uint32_t k0 = *(const uint32_t*)(hb + (size_t)u0 * 128 + l * 2);
    uint32_t k1 = *(const uint32_t*)(hb + (size_t)u1 * 128 + l * 2);
    uint32_t k2 = *(const uint32_t*)(hb + (size_t)u2 * 128 + l * 2);
    uint32_t k3 = *(const uint32_t*)(hb + (size_t)u3 * 128 + l * 2);
    uint32_t k4 = *(const uint32_t*)(hb + (size_t)u4 * 128 + l * 2);
    uint32_t k5 = *(const uint32_t*)(hb + (size_t)u5 * 128 + l * 2);
    uint32_t k6 = *(const uint32_t*)(hb + (size_t)u6 * 128 + l * 2);
    uint32_t k7 = *(const uint32_t*)(hb + (size_t)u7 * 128 + l * 2);
    a0 += w0 * bf2f(k0 & 0xffffu) + w1 * bf2f(k1 & 0xffffu)
        + w2 * bf2f(k2 & 0xffffu) + w3 * bf2f(k3 & 0xffffu)
        + w4 * bf2f(k4 & 0xffffu) + w5 * bf2f(k5 & 0xffffu)
        + w6 * bf2f(k6 & 0xffffu) + w7 * bf2f(k7 & 0xffffu);
    a1 += w0 * bf2f(k0 >> 16) + w1 * bf2f(k1 >> 16)
        + w2 * bf2f(k2 >> 16) + w3 * bf2f(k3 >> 16)
        + w4 * bf2f(k4 >> 16) + w5 * bf2f(k5 >> 16)
        + w6 * bf2f(k6 >> 16) + w7 * bf2f(k7 >> 16);
  }
  for (; e + 4 <= e1; e += 4) {
    int u0 = colx[e], u1 = colx[e + 1], u2 = colx[e + 2], u3 = colx[e + 3];
    float w0 = wgt[e], w1 = wgt[e + 1], w2 = wgt[e + 2], w3 = wgt[e + 3];
    uint32_t k0 = *(const uint32_t*)(hb + (size_t)u0 * 128 + l * 2);
    uint32_t k1 = *(const uint32_t*)(hb + (size_t)u1 * 128 + l * 2);
    uint32_t k2 = *(const uint32_t*)(hb + (size_t)u2 * 128 + l * 2);
    uint32_t k3 = *(const uint32_t*)(hb + (size_t)u3 * 128 + l * 2);
    a0 += w0 * bf2f(k0 & 0xffffu) + w1 * bf2f(k1 & 0xffffu)
        + w2 * bf2f(k2 & 0xffffu) + w3 * bf2f(k3 & 0xffffu);
    a1 += w0 * bf2f(k0 >> 16) + w1 * bf2f(k1 >> 16)
        + w2 * bf2f(k2 >> 16) + w3 * bf2f(k3 >> 16);
  }
  for (; e < e1; ++e) {
    int u = colx[e];
    float wv = wgt[e];
    uint32_t pk = *(const uint32_t*)(hb + (size_t)u * 128 + l * 2);
    a0 += wv * bf2f(pk & 0xffffu);
    a1 += wv * bf2f(pk >> 16);
  }
  uint32_t o = f2bf(a0) | (f2bf(a1) << 16);
  *(uint32_t*)(out + (size_t)p * 128 + l * 2) = o;
}

// ---------- MLP stage 1 as MFMA split-K GEMM (KC=128, ~39KB LDS, 4 blk/CU) ----------
__global__ __launch_bounds__(256) void k_mlp1(
    const u16* __restrict__ h3, const float* __restrict__ W1, float* __restrict__ part)
{
  __shared__ u16 sA[32][136];    // 8.7 KB (128 + 8 pad)
  __shared__ u16 sB[112][136];   // 30.5 KB
  const int t = threadIdx.x;
  const int blk = blockIdx.x;
  const int j0 = blk * KC;
  // stage h3: thread t -> row t>>3, 16 cols at (t&7)*16
  {
    int r = t >> 3, c = (t & 7) * 16;
    const u16* src = h3 + (size_t)r * 262144 + j0 + c;
    *(bf16x8*)&sA[r][c] = *(const bf16x8*)src;
    *(bf16x8*)&sA[r][c + 8] = *(const bf16x8*)(src + 8);
  }
  // stage W1^T: 1600 tasks (jp 0..63, mq 0..24), 7 iters
  for (int it = 0; it < 7; ++it) {
    int task = it * 256 + t;
    if (task < 1600) {
      int jp = task / 25, mq = task % 25;
      const float* wp = W1 + (size_t)(j0 + 2 * jp) * 100 + mq * 4;
      float4 fa = *(const float4*)wp;
      float4 fb = *(const float4*)(wp + 100);
      uint32_t p0 = f2bf(fa.x) | (f2bf(fb.x) << 16);
      uint32_t p1 = f2bf(fa.y) | (f2bf(fb.y) << 16);
      uint32_t p2 = f2bf(fa.z) | (f2bf(fb.z) << 16);
      uint32_t p3 = f2bf(fa.w) | (f2bf(fb.w) << 16);
      int m = mq * 4;
      *(uint32_t*)&sB[m + 0][2 * jp] = p0;
      *(uint32_t*)&sB[m + 1][2 * jp] = p1;
      *(uint32_t*)&sB[m + 2][2 * jp] = p2;
      *(uint32_t*)&sB[m + 3][2 * jp] = p3;
    }
  }
  __syncthreads();
  const int w = t >> 6, l = t & 63;
  const int mt = w >> 1, nh = w & 1;
  const int nt0 = nh * 4, ntn = nh ? 3 : 4;
  const int lm = l & 15, lk8 = (l >> 4) * 8;
  f32x4 acc[4];
#pragma unroll
  for (int n = 0; n < 4; ++n) acc[n] = (f32x4){0.f, 0.f, 0.f, 0.f};
#pragma unroll
  for (int kk = 0; kk < 4; ++kk) {
    int ko = kk * 32 + lk8;
    bf16x8 af = *(const bf16x8*)&sA[mt * 16 + lm][ko];
#pragma unroll
    for (int n = 0; n < 4; ++n) {
      if (n < ntn) {
        bf16x8 bfr = *(const bf16x8*)&sB[(nt0 + n) * 16 + lm][ko];
        acc[n] = __builtin_amdgcn_mfma_f32_16x16x32_bf16(af, bfr, acc[n], 0, 0, 0);
      }
    }
  }
  const int rq = (l >> 4) * 4;
#pragma unroll
  for (int n = 0; n < 4; ++n) {
    if (n < ntn) {
      int m = (nt0 + n) * 16 + lm;
#pragma unroll
      for (int q = 0; q < 4; ++q) {
        int b = mt * 16 + rq + q;
        part[((size_t)blk * 32 + b) * PW + m] = acc[n][q];
      }
    }
  }
}

// ---------- reduce stage 1: 32 ranges x 64 rows, 448 blocks ----------
__global__ __launch_bounds__(256) void k_red(
    const float* __restrict__ part, float* __restrict__ part2)
{
  int e = blockIdx.x * 256 + threadIdx.x;   // element in [0, 32*PW) == 3584
  int rg = blockIdx.y;
  if (e >= 32 * PW) return;
  const float* p = part + (size_t)rg * 64 * (32 * PW) + e;
  float s0 = 0.f, s1 = 0.f, s2 = 0.f, s3 = 0.f;
  for (int r = 0; r < 64; r += 4) {
    s0 += p[(size_t)(r + 0) * (32 * PW)];
    s1 += p[(size_t)(r + 1) * (32 * PW)];
    s2 += p[(size_t)(r + 2) * (32 * PW)];
    s3 += p[(size_t)(r + 3) * (32 * PW)];
  }
  part2[rg * (32 * PW) + e] = (s0 + s1) + (s2 + s3);
}

// ---------- MLP stage 2 ----------
__global__ __launch_bounds__(128) void k_mlp2(
    const float* __restrict__ part2, const float* __restrict__ b1,
    const float* __restrict__ W2, const float* __restrict__ b2, float* __restrict__ out)
{
  __shared__ float sh[100];
  int b = blockIdx.x, t = threadIdx.x;
  if (t < 100) {
    float s = 0.f;
#pragma unroll
    for (int rg = 0; rg < NRG; ++rg)
      s += part2[rg * (32 * PW) + b * PW + t];
    float h = fmaxf(s + b1[t], 0.f);
    sh[t] = h * W2[t];
  }
  __syncthreads();
  if (t == 0) {
    float s = 0.f;
    for (int m = 0; m < 100; ++m) s += sh[m];
    out[b] = s + b2[0];
  }
}

extern "C" void kernel_launch(void* const* d_in, const int* in_sizes, int n_in,
                              void* d_out, int out_size, void* d_ws, size_t ws_size,
                              hipStream_t stream) {
  (void)in_sizes; (void)n_in; (void)out_size; (void)ws_size;
  const float* x      = (const float*)d_in[0];
  const int* edge     = (const int*)d_in[1];
  const float* conv_w = (const float*)d_in[2];
  const float* conv_b = (const float*)d_in[3];
  const float* gW1    = (const float*)d_in[4];
  const float* gb1    = (const float*)d_in[5];
  const float* gW2    = (const float*)d_in[6];
  const float* gb2    = (const float*)d_in[7];
  const float* W1     = (const float*)d_in[8];
  const float* b1     = (const float*)d_in[9];
  const float* W2     = (const float*)d_in[10];
  const float* b2     = (const float*)d_in[11];
  float* out = (float*)d_out;

  char* ws = (char*)d_ws;
  size_t off = 0;
  auto alloc = [&](size_t bytes) {
    void* p = ws + off;
    off = (off + bytes + 255) & ~(size_t)255;
    return p;
  };
  u16* bufA   = (u16*)alloc(8388608ull * 2);   // (B,N,128) ping
  u16* bufB   = (u16*)alloc(8388608ull * 2);   // (B,N,128) pong
  u16* Wtb    = (u16*)alloc(49152ull * 2);     // conv_w bf16 [c][384]
  u16* g1t    = (u16*)alloc(16384ull * 2);
  u16* g2t    = (u16*)alloc(16384ull * 2);
  int* cnt    = (int*)alloc(2048 * 4);
  int* cursor = (int*)alloc(2048 * 4);
  int* rowp   = (int*)alloc(2052 * 4);
  int* colx   = (int*)alloc(34816 * 4);
  float* wgt  = (float*)alloc(34816 * 4);
  float* part = (float*)alloc((size_t)NBLK * 32 * PW * 4);   // 29.36 MB
  float* part2= (float*)alloc((size_t)NRG * (32 * PW) * 4);

  // prep (conv_w cvt, g transposes, csr init)
  k_prep<<<120, 256, 0, stream>>>((const float4*)conv_w, (uint2*)Wtb,
                                  gW1, gW2, g1t, g2t, cnt, cursor);
  // CSR chain
  k_count<<<128, 256, 0, stream>>>(edge, cnt);
  k_scan<<<1, 1024, 0, stream>>>(cnt, rowp);
  k_fill<<<(NEDGE + NN + 255) / 256, 256, 0, stream>>>(edge, cnt, rowp, cursor, colx, wgt);

  // conv as GEMM with fused x cvt: (65536 x 384) @ (384 x 128), 64-row tiles
  k_gemmf<<<1024, 256, 0, stream>>>(x, Wtb, conv_b, bufA, 384, 256);
  // GCN layer 1
  k_gather<<<16384, 256, 0, stream>>>(bufA, rowp, colx, wgt, bufB);
  k_gemm<<<1024, 256, 0, stream>>>(bufB, g1t, gb1, bufA, 128);
  // GCN layer 2
  k_gather<<<16384, 256, 0, stream>>>(bufA, rowp, colx, wgt, bufB);
  k_gemm<<<1024, 256, 0, stream>>>(bufB, g2t, gb2, bufA, 128);
  // MLP
  k_mlp1<<<NBLK, 256, 0, stream>>>(bufA, W1, part);
  k_red<<<dim3(14, NRG), 256, 0, stream>>>(part, part2);
  k_mlp2<<<32, 128, 0, stream>>>(part2, b1, W2, b2, out);
}

// Round 21
// 167.284 us; speedup vs baseline: 1.0111x; 1.0111x over previous
//
#include <hip/hip_runtime.h>
#include <stdint.h>

typedef unsigned short u16;
typedef __attribute__((ext_vector_type(8))) short bf16x8;
typedef __attribute__((ext_vector_type(4))) float f32x4;

#define NN 2048
#define NEDGE 32768
#define NBLK 1024      // mlp1 split-K blocks
#define KC 256         // j-chunk per mlp1 block (NBLK*KC == 262144)
#define NRG 16         // reduce ranges (NBLK/64)
#define PW 112         // padded N for mlp1 (7 tiles of 16; 100 real)

__device__ __forceinline__ float bf2f(uint32_t u) {
  union { uint32_t i; float f; } c; c.i = u << 16; return c.f;
}
__device__ __forceinline__ uint32_t f2bf(float f) {
  union { float f; uint32_t i; } c; c.f = f;
  uint32_t x = c.i;
  return (x + 0x7fffu + ((x >> 16) & 1u)) >> 16;
}

// ---------- prep: conv_w cvt (0..47), gW1/gW2 transpose (48..111), csr-init (112..119) ----------
__global__ void k_prep(const float4* __restrict__ cw, uint2* __restrict__ wtb,
                       const float* __restrict__ g1, const float* __restrict__ g2,
                       u16* __restrict__ o1, u16* __restrict__ o2,
                       int* __restrict__ cnt, int* __restrict__ cursor) {
  int blk = blockIdx.x;
  if (blk < 48) {
    int i = blk * 256 + threadIdx.x;         // 12288 exact (49152/4)
    float4 v = cw[i];
    uint2 o;
    o.x = f2bf(v.x) | (f2bf(v.y) << 16);
    o.y = f2bf(v.z) | (f2bf(v.w) << 16);
    wtb[i] = o;
  } else if (blk < 112) {
    int i = (blk - 48) * 256 + threadIdx.x;  // 16384 exact
    int r = i >> 7, c = i & 127;
    o1[i] = (u16)f2bf(g1[c * 128 + r]);
    o2[i] = (u16)f2bf(g2[c * 128 + r]);
  } else {
    int i = (blk - 112) * 256 + threadIdx.x; // 2048 exact
    cnt[i] = 1; cursor[i] = 0;               // self-loop baseline
  }
}

// ---------- CSR build (parallel chain) ----------
__global__ void k_count(const int* __restrict__ edge, int* __restrict__ cnt) {
  int i = blockIdx.x * 256 + threadIdx.x;
  if (i < NEDGE) atomicAdd(&cnt[edge[NEDGE + i]], 1);
}

__global__ __launch_bounds__(1024) void k_scan(const int* __restrict__ cnt, int* __restrict__ rowp) {
  __shared__ int s[1024];
  int t = threadIdx.x;
  int c0 = cnt[2 * t], c1 = cnt[2 * t + 1];
  s[t] = c0 + c1;
  __syncthreads();
  for (int off = 1; off < 1024; off <<= 1) {
    int v = (t >= off) ? s[t - off] : 0;
    __syncthreads();
    s[t] += v;
    __syncthreads();
  }
  int excl = s[t] - c0 - c1;
  rowp[2 * t] = excl;
  rowp[2 * t + 1] = excl + c0;
  if (t == 1023) rowp[2048] = s[t];
}

__global__ void k_fill(const int* __restrict__ edge, const int* __restrict__ cnt,
                       const int* __restrict__ rowp, int* __restrict__ cursor,
                       int* __restrict__ colx, float* __restrict__ wgt) {
  int i = blockIdx.x * 256 + threadIdx.x;
  if (i >= NEDGE + NN) return;
  int s, d;
  if (i < NEDGE) { s = edge[i]; d = edge[NEDGE + i]; }
  else { s = i - NEDGE; d = s; }
  float wv = rsqrtf((float)cnt[s] * (float)cnt[d]);
  int pos = atomicAdd(&cursor[d], 1);
  int idx = rowp[d] + pos;
  colx[idx] = s;
  wgt[idx] = wv;
}

// ---------- conv GEMM, 64-row tiles (1024 blocks, 16 waves/CU):
// A = fp32 x inline-cvt (reg-staged, swizzled), B = bf16 global_load_lds ----------
__global__ __launch_bounds__(256) void k_gemmf(
    const float* __restrict__ A, const u16* __restrict__ Bt,
    const float* __restrict__ bias, u16* __restrict__ C,
    int K, int bExtra)
{
  __shared__ u16 lA[64 * 64];     // 8 KB
  __shared__ u16 lB[128 * 64];    // 16 KB
  const int t = threadIdx.x;
  const int Mbase = blockIdx.x * 64;
  const size_t aBase = (size_t)Mbase * 128 + (size_t)(Mbase >> 11) * bExtra;
  const int w = t >> 6, l = t & 63;
  const int wrN = w * 32;
  const int lm = l & 15, lkh = l >> 4;
  const int rph0 = t >> 3, pc = t & 7;       // B staging
  const int row4 = t >> 2, qf = t & 3;       // A staging: row, quarter (16 fp32)
  f32x4 acc[4][2];
#pragma unroll
  for (int i = 0; i < 4; ++i)
#pragma unroll
    for (int j = 0; j < 2; ++j)
      acc[i][j] = (f32x4){0.f, 0.f, 0.f, 0.f};

  for (int kc = 0; kc < K; kc += 64) {
    __syncthreads();
    // B: async DMA, linear dest, pre-swizzled source (128 rows)
#pragma unroll
    for (int it = 0; it < 4; ++it) {
      int r = it * 32 + rph0;
      int lc = pc ^ (r & 7);
      char* dstB = (char*)lB + it * 4096 + w * 1024;
      __builtin_amdgcn_global_load_lds(
          (const void*)(Bt + (size_t)r * K + kc + lc * 8), dstB, 16, 0, 0);
    }
    // A: fp32 load + cvt + swizzled ds_write (quarter row = 16 floats = 2 chunks)
    {
      const float4* src = (const float4*)(A + aBase + (size_t)row4 * 128 + kc + qf * 16);
      float4 f[4];
#pragma unroll
      for (int c = 0; c < 4; ++c) f[c] = src[c];
      uint4 pk0, pk1;
      pk0.x = f2bf(f[0].x) | (f2bf(f[0].y) << 16);
      pk0.y = f2bf(f[0].z) | (f2bf(f[0].w) << 16);
      pk0.z = f2bf(f[1].x) | (f2bf(f[1].y) << 16);
      pk0.w = f2bf(f[1].z) | (f2bf(f[1].w) << 16);
      pk1.x = f2bf(f[2].x) | (f2bf(f[2].y) << 16);
      pk1.y = f2bf(f[2].z) | (f2bf(f[2].w) << 16);
      pk1.z = f2bf(f[3].x) | (f2bf(f[3].y) << 16);
      pk1.w = f2bf(f[3].z) | (f2bf(f[3].w) << 16);
      int ch0 = qf * 2, ch1 = qf * 2 + 1;
      *(uint4*)((char*)lA + row4 * 128 + ((ch0 ^ (row4 & 7)) << 4)) = pk0;
      *(uint4*)((char*)lA + row4 * 128 + ((ch1 ^ (row4 & 7)) << 4)) = pk1;
    }
    __syncthreads();
#pragma unroll
    for (int kk = 0; kk < 2; ++kk) {
      int lc = kk * 4 + lkh;
      bf16x8 af[4], bfr[2];
#pragma unroll
      for (int i = 0; i < 4; ++i) {
        int R = i * 16 + lm;
        af[i] = *(const bf16x8*)((const char*)lA + R * 128 + ((lc ^ (R & 7)) << 4));
      }
#pragma unroll
      for (int j = 0; j < 2; ++j) {
        int R = wrN + j * 16 + lm;
        bfr[j] = *(const bf16x8*)((const char*)lB + R * 128 + ((lc ^ (R & 7)) << 4));
      }
#pragma unroll
      for (int i = 0; i < 4; ++i)
#pragma unroll
        for (int j = 0; j < 2; ++j)
          acc[i][j] = __builtin_amdgcn_mfma_f32_16x16x32_bf16(af[i], bfr[j], acc[i][j], 0, 0, 0);
    }
  }
  const int rq = (l >> 4) * 4;
#pragma unroll
  for (int i = 0; i < 4; ++i) {
#pragma unroll
    for (int j = 0; j < 2; ++j) {
      int col = wrN + j * 16 + lm;
      float bv = bias[col];
#pragma unroll
      for (int q = 0; q < 4; ++q) {
        int row = Mbase + i * 16 + rq + q;
        float v = acc[i][j][q] + bv;
        v = fmaxf(v, 0.f);
        C[(size_t)row * 128 + col] = (u16)f2bf(v);
      }
    }
  }
}

// ---------- GCN GEMM, 64-row tiles (bf16 A, both via global_load_lds) ----------
__global__ __launch_bounds__(256) void k_gemm(
    const u16* __restrict__ A, const u16* __restrict__ Bt,
    const float* __restrict__ bias, u16* __restrict__ C,
    int K)
{
  __shared__ u16 lA[64 * 64];     // 8 KB
  __shared__ u16 lB[128 * 64];    // 16 KB
  const int t = threadIdx.x;
  const int Mbase = blockIdx.x * 64;
  const size_t aBase = (size_t)Mbase * 128;
  const int w = t >> 6, l = t & 63;
  const int wrN = w * 32;
  const int lm = l & 15, lkh = l >> 4;
  const int rph0 = t >> 3, pc = t & 7;
  f32x4 acc[4][2];
#pragma unroll
  for (int i = 0; i < 4; ++i)
#pragma unroll
    for (int j = 0; j < 2; ++j)
      acc[i][j] = (f32x4){0.f, 0.f, 0.f, 0.f};

  for (int kc = 0; kc < K; kc += 64) {
    __syncthreads();
    // A: 64 rows, 2 issue rounds
#pragma unroll
    for (int it = 0; it < 2; ++it) {
      int r = it * 32 + rph0;
      int lc = pc ^ (r & 7);
      char* dstA = (char*)lA + it * 4096 + w * 1024;
      __builtin_amdgcn_global_load_lds(
          (const void*)(A + aBase + (size_t)r * 128 + kc + lc * 8), dstA, 16, 0, 0);
    }
    // B: 128 rows, 4 issue rounds
#pragma unroll
    for (int it = 0; it < 4; ++it) {
      int r = it * 32 + rph0;
      int lc = pc ^ (r & 7);
      char* dstB = (char*)lB + it * 4096 + w * 1024;
      __builtin_amdgcn_global_load_lds(
          (const void*)(Bt + (size_t)r * K + kc + lc * 8), dstB, 16, 0, 0);
    }
    __syncthreads();
#pragma unroll
    for (int kk = 0; kk < 2; ++kk) {
      int lc = kk * 4 + lkh;
      bf16x8 af[4], bfr[2];
#pragma unroll
      for (int i = 0; i < 4; ++i) {
        int R = i * 16 + lm;
        af[i] = *(const bf16x8*)((const char*)lA + R * 128 + ((lc ^ (R & 7)) << 4));
      }
#pragma unroll
      for (int j = 0; j < 2; ++j) {
        int R = wrN + j * 16 + lm;
        bfr[j] = *(const bf16x8*)((const char*)lB + R * 128 + ((lc ^ (R & 7)) << 4));
      }
#pragma unroll
      for (int i = 0; i < 4; ++i)
#pragma unroll
        for (int j = 0; j < 2; ++j)
          acc[i][j] = __builtin_amdgcn_mfma_f32_16x16x32_bf16(af[i], bfr[j], acc[i][j], 0, 0, 0);
    }
  }
  const int rq = (l >> 4) * 4;
#pragma unroll
  for (int i = 0; i < 4; ++i) {
#pragma unroll
    for (int j = 0; j < 2; ++j) {
      int col = wrN + j * 16 + lm;
      float bv = bias[col];
#pragma unroll
      for (int q = 0; q < 4; ++q) {
        int row = Mbase + i * 16 + rq + q;
        float v = acc[i][j][q] + bv;
        v = fmaxf(v, 0.f);
        C[(size_t)row * 128 + col] = (u16)f2bf(v);
      }
    }
  }
}

// ---------- sparse gather: one wave per (b,v), 8-edge ILP, XCD swizzle ----------
__global__ __launch_bounds__(256) void k_gather(
    const u16* __restrict__ h, const int* __restrict__ rowp,
    const int* __restrict__ colx, const float* __restrict__ wgt,
    u16* __restrict__ out)
{
  int w = threadIdx.x >> 6, l = threadIdx.x & 63;
  int bid = blockIdx.x;
  int sb = (bid & 7) * 2048 + (bid >> 3);   // bijective XCD swizzle (16384 blocks)
  int p = sb * 4 + w;                       // 0..65535
  int b = p >> 11, v = p & 2047;
  int e0 = rowp[v], e1 = rowp[v + 1];
  const u16* hb = h + (size_t)b * (2048 * 128);
  float a0 = 0.f, a1 = 0.f;
  int e = e0;
  for (; e + 8 <= e1; e += 8) {
    int u0 = colx[e], u1 = colx[e + 1], u2 = colx[e + 2], u3 = colx[e + 3];
    int u4 = colx[e + 4], u5 = colx[e + 5], u6 = colx[e + 6], u7 = colx[e + 7];
    float w0 = wgt[e], w1 = wgt[e + 1], w2 = wgt[e + 2], w3 = wgt[e + 3];
    float w4 = wgt[e + 4], w5 = wgt[e + 5], w6 = wgt[e + 6], w7 = wgt[e + 7];
    uint32_t k0 = *(const uint32_t*)(hb + (size_t)u0 * 128 + l * 2);
    uint32_t k1 = *(const uint32_t*)(hb + (size_t)u1 * 128 + l * 2);
    uint32_t k2 = *(const uint32_t*)(hb + (size_t)u2 * 128 + l * 2);
    uint32_t k3 = *(const uint32_t*)(hb + (size_t)u3 * 128 + l * 2);
    uint32_t k4 = *(const uint32_t*)(hb + (size_t)u4 * 128 + l * 2);
    uint32_t k5 = *(const uint32_t*)(hb + (size_t)u5 * 128 + l * 2);
    uint32_t k6 = *(const uint32_t*)(hb + (size_t)u6 * 128 + l * 2);
    uint32_t k7 = *(const uint32_t*)(hb + (size_t)u7 * 128 + l * 2);
    a0 += w0 * bf2f(k0 & 0xffffu) + w1 * bf2f(k1 & 0xffffu)
        + w2 * bf2f(k2 & 0xffffu) + w3 * bf2f(k3 & 0xffffu)
        + w4 * bf2f(k4 & 0xffffu) + w5 * bf2f(k5 & 0xffffu)
        + w6 * bf2f(k6 & 0xffffu) + w7 * bf2f(k7 & 0xffffu);
    a1 += w0 * bf2f(k0 >> 16) + w1 * bf2f(k1 >> 16)
        + w2 * bf2f(k2 >> 16) + w3 * bf2f(k3 >> 16)
        + w4 * bf2f(k4 >> 16) + w5 * bf2f(k5 >> 16)
        + w6 * bf2f(k6 >> 16) + w7 * bf2f(k7 >> 16);
  }
  for (; e + 4 <= e1; e += 4) {
    int u0 = colx[e], u1 = colx[e + 1], u2 = colx[e + 2], u3 = colx[e + 3];
    float w0 = wgt[e], w1 = wgt[e + 1], w2 = wgt[e + 2], w3 = wgt[e + 3];
    uint32_t k0 = *(const uint32_t*)(hb + (size_t)u0 * 128 + l * 2);
    uint32_t k1 = *(const uint32_t*)(hb + (size_t)u1 * 128 + l * 2);
    uint32_t k2 = *(const uint32_t*)(hb + (size_t)u2 * 128 + l * 2);
    uint32_t k3 = *(const uint32_t*)(hb + (size_t)u3 * 128 + l * 2);
    a0 += w0 * bf2f(k0 & 0xffffu) + w1 * bf2f(k1 & 0xffffu)
        + w2 * bf2f(k2 & 0xffffu) + w3 * bf2f(k3 & 0xffffu);
    a1 += w0 * bf2f(k0 >> 16) + w1 * bf2f(k1 >> 16)
        + w2 * bf2f(k2 >> 16) + w3 * bf2f(k3 >> 16);
  }
  for (; e < e1; ++e) {
    int u = colx[e];
    float wv = wgt[e];
    uint32_t pk = *(const uint32_t*)(hb + (size_t)u * 128 + l * 2);
    a0 += wv * bf2f(pk & 0xffffu);
    a1 += wv * bf2f(pk >> 16);
  }
  uint32_t o = f2bf(a0) | (f2bf(a1) << 16);
  *(uint32_t*)(out + (size_t)p * 128 + l * 2) = o;
}

// ---------- MLP stage 1 as MFMA split-K GEMM ----------
__global__ __launch_bounds__(256) void k_mlp1(
    const u16* __restrict__ h3, const float* __restrict__ W1, float* __restrict__ part)
{
  __shared__ u16 sA[32][264];
  __shared__ u16 sB[112][264];
  const int t = threadIdx.x;
  const int blk = blockIdx.x;
  const int j0 = blk * KC;
  {
    int r = t >> 3, c = (t & 7) * 32;
    const u16* src = h3 + (size_t)r * 262144 + j0 + c;
#pragma unroll
    for (int u = 0; u < 4; ++u)
      *(bf16x8*)&sA[r][c + u * 8] = *(const bf16x8*)(src + u * 8);
  }
  for (int it = 0; it < 13; ++it) {
    int task = it * 256 + t;
    if (task < 3200) {
      int jp = task / 25, mq = task % 25;
      const float* wp = W1 + (size_t)(j0 + 2 * jp) * 100 + mq * 4;
      float4 fa = *(const float4*)wp;
      float4 fb = *(const float4*)(wp + 100);
      uint32_t p0 = f2bf(fa.x) | (f2bf(fb.x) << 16);
      uint32_t p1 = f2bf(fa.y) | (f2bf(fb.y) << 16);
      uint32_t p2 = f2bf(fa.z) | (f2bf(fb.z) << 16);
      uint32_t p3 = f2bf(fa.w) | (f2bf(fb.w) << 16);
      int m = mq * 4;
      *(uint32_t*)&sB[m + 0][2 * jp] = p0;
      *(uint32_t*)&sB[m + 1][2 * jp] = p1;
      *(uint32_t*)&sB[m + 2][2 * jp] = p2;
      *(uint32_t*)&sB[m + 3][2 * jp] = p3;
    }
  }
  __syncthreads();
  const int w = t >> 6, l = t & 63;
  const int mt = w >> 1, nh = w & 1;
  const int nt0 = nh * 4, ntn = nh ? 3 : 4;
  const int lm = l & 15, lk8 = (l >> 4) * 8;
  f32x4 acc[4];
#pragma unroll
  for (int n = 0; n < 4; ++n) acc[n] = (f32x4){0.f, 0.f, 0.f, 0.f};
#pragma unroll
  for (int kk = 0; kk < 8; ++kk) {
    int ko = kk * 32 + lk8;
    bf16x8 af = *(const bf16x8*)&sA[mt * 16 + lm][ko];
#pragma unroll
    for (int n = 0; n < 4; ++n) {
      if (n < ntn) {
        bf16x8 bfr = *(const bf16x8*)&sB[(nt0 + n) * 16 + lm][ko];
        acc[n] = __builtin_amdgcn_mfma_f32_16x16x32_bf16(af, bfr, acc[n], 0, 0, 0);
      }
    }
  }
  const int rq = (l >> 4) * 4;
#pragma unroll
  for (int n = 0; n < 4; ++n) {
    if (n < ntn) {
      int m = (nt0 + n) * 16 + lm;
#pragma unroll
      for (int q = 0; q < 4; ++q) {
        int b = mt * 16 + rq + q;
        part[((size_t)blk * 32 + b) * PW + m] = acc[n][q];
      }
    }
  }
}

// ---------- reduce stage 1: 16 ranges x 64 rows, 224 blocks ----------
__global__ __launch_bounds__(256) void k_red(
    const float* __restrict__ part, float* __restrict__ part2)
{
  int e = blockIdx.x * 256 + threadIdx.x;   // element in [0, 32*PW) == 3584
  int rg = blockIdx.y;
  if (e >= 32 * PW) return;
  const float* p = part + (size_t)rg * 64 * (32 * PW) + e;
  float s0 = 0.f, s1 = 0.f, s2 = 0.f, s3 = 0.f;
  for (int r = 0; r < 64; r += 4) {
    s0 += p[(size_t)(r + 0) * (32 * PW)];
    s1 += p[(size_t)(r + 1) * (32 * PW)];
    s2 += p[(size_t)(r + 2) * (32 * PW)];
    s3 += p[(size_t)(r + 3) * (32 * PW)];
  }
  part2[rg * (32 * PW) + e] = (s0 + s1) + (s2 + s3);
}

// ---------- MLP stage 2 ----------
__global__ __launch_bounds__(128) void k_mlp2(
    const float* __restrict__ part2, const float* __restrict__ b1,
    const float* __restrict__ W2, const float* __restrict__ b2, float* __restrict__ out)
{
  __shared__ float sh[100];
  int b = blockIdx.x, t = threadIdx.x;
  if (t < 100) {
    float s = 0.f;
#pragma unroll
    for (int rg = 0; rg < NRG; ++rg)
      s += part2[rg * (32 * PW) + b * PW + t];
    float h = fmaxf(s + b1[t], 0.f);
    sh[t] = h * W2[t];
  }
  __syncthreads();
  if (t == 0) {
    float s = 0.f;
    for (int m = 0; m < 100; ++m) s += sh[m];
    out[b] = s + b2[0];
  }
}

extern "C" void kernel_launch(void* const* d_in, const int* in_sizes, int n_in,
                              void* d_out, int out_size, void* d_ws, size_t ws_size,
                              hipStream_t stream) {
  (void)in_sizes; (void)n_in; (void)out_size; (void)ws_size;
  const float* x      = (const float*)d_in[0];
  const int* edge     = (const int*)d_in[1];
  const float* conv_w = (const float*)d_in[2];
  const float* conv_b = (const float*)d_in[3];
  const float* gW1    = (const float*)d_in[4];
  const float* gb1    = (const float*)d_in[5];
  const float* gW2    = (const float*)d_in[6];
  const float* gb2    = (const float*)d_in[7];
  const float* W1     = (const float*)d_in[8];
  const float* b1     = (const float*)d_in[9];
  const float* W2     = (const float*)d_in[10];
  const float* b2     = (const float*)d_in[11];
  float* out = (float*)d_out;

  char* ws = (char*)d_ws;
  size_t off = 0;
  auto alloc = [&](size_t bytes) {
    void* p = ws + off;
    off = (off + bytes + 255) & ~(size_t)255;
    return p;
  };
  u16* bufA   = (u16*)alloc(8388608ull * 2);   // (B,N,128) ping
  u16* bufB   = (u16*)alloc(8388608ull * 2);   // (B,N,128) pong
  u16* Wtb    = (u16*)alloc(49152ull * 2);     // conv_w bf16 [c][384]
  u16* g1t    = (u16*)alloc(16384ull * 2);
  u16* g2t    = (u16*)alloc(16384ull * 2);
  int* cnt    = (int*)alloc(2048 * 4);
  int* cursor = (int*)alloc(2048 * 4);
  int* rowp   = (int*)alloc(2052 * 4);
  int* colx   = (int*)alloc(34816 * 4);
  float* wgt  = (float*)alloc(34816 * 4);
  float* part = (float*)alloc((size_t)NBLK * 32 * PW * 4);   // 14.68 MB
  float* part2= (float*)alloc((size_t)NRG * (32 * PW) * 4);

  // prep (conv_w cvt, g transposes, csr init)
  k_prep<<<120, 256, 0, stream>>>((const float4*)conv_w, (uint2*)Wtb,
                                  gW1, gW2, g1t, g2t, cnt, cursor);
  // CSR chain
  k_count<<<128, 256, 0, stream>>>(edge, cnt);
  k_scan<<<1, 1024, 0, stream>>>(cnt, rowp);
  k_fill<<<(NEDGE + NN + 255) / 256, 256, 0, stream>>>(edge, cnt, rowp, cursor, colx, wgt);

  // conv as GEMM with fused x cvt: (65536 x 384) @ (384 x 128), 64-row tiles
  k_gemmf<<<1024, 256, 0, stream>>>(x, Wtb, conv_b, bufA, 384, 256);
  // GCN layer 1
  k_gather<<<16384, 256, 0, stream>>>(bufA, rowp, colx, wgt, bufB);
  k_gemm<<<1024, 256, 0, stream>>>(bufB, g1t, gb1, bufA, 128);
  // GCN layer 2
  k_gather<<<16384, 256, 0, stream>>>(bufA, rowp, colx, wgt, bufB);
  k_gemm<<<1024, 256, 0, stream>>>(bufB, g2t, gb2, bufA, 128);
  // MLP
  k_mlp1<<<NBLK, 256, 0, stream>>>(bufA, W1, part);
  k_red<<<dim3(14, NRG), 256, 0, stream>>>(part, part2);
  k_mlp2<<<32, 128, 0, stream>>>(part2, b1, W2, b2, out);
}